// Round 1
// baseline (5061.707 us; speedup 1.0000x reference)
//
#include <hip/hip_runtime.h>
#include <math.h>

// Problem constants (from reference setup_inputs: N=2, C=64, H=96, W=96, PATCH=3)
static constexpr int NITEM = 2;
static constexpr int C = 64;
static constexpr int H = 96;
static constexpr int W = 96;
static constexpr int HP = 94;          // H - 3 + 1
static constexpr int NP = HP * HP;     // 8836 patch positions
static constexpr int NSEG = 4;
static constexpr int SEGLEN = NP / NSEG; // 2209 exactly
static constexpr int MT = 128;         // input-position tile
static constexpr int NT = 128;         // ref-position tile
static constexpr int KC = 16;          // K chunk (one patch-pixel, 16 channels)
static constexpr int NMTILE = (NP + MT - 1) / MT; // 70

// ---------------- Kernel 1: per-pixel channel L2 normalize + NCHW->NHWC ----------------
__global__ __launch_bounds__(256) void normalize_kernel(
    const float* __restrict__ f1, const float* __restrict__ f2,
    float* __restrict__ fiN, float* __restrict__ frN, float* __restrict__ ssn)
{
    int t = blockIdx.x * 256 + threadIdx.x;
    const int perTensor = NITEM * H * W; // 18432
    if (t >= 2 * perTensor) return;
    int which = t / perTensor;
    int p = t - which * perTensor;           // (n, pixel) flat
    int n = p / (H * W);
    int pix = p - n * (H * W);
    const float* src = (which ? f2 : f1) + (size_t)n * C * H * W + pix;
    float s = 0.f;
    #pragma unroll
    for (int c = 0; c < C; c++) {
        float v = src[c * (H * W)];
        s = fmaf(v, v, s);
    }
    float norm = sqrtf(s);
    float scale = 1.0f / fmaxf(norm, 1e-12f);
    float* dst = (which ? frN : fiN) + (size_t)p * C;
    #pragma unroll
    for (int c = 0; c < C; c++) {
        dst[c] = src[c * (H * W)] * scale;
    }
    if (which) ssn[p] = s * scale * scale;   // sum of squares of normalized pixel (≈1)
}

// ---------------- Kernel 2: ref patch inverse norms: 1/(sqrt(3x3 box sum)+1e-5) ----------------
__global__ __launch_bounds__(256) void refnorm_kernel(
    const float* __restrict__ ssn, float* __restrict__ invn)
{
    int t = blockIdx.x * 256 + threadIdx.x;
    if (t >= NITEM * NP) return;
    int n = t / NP;
    int r = t - n * NP;
    int yr = r / HP, xr = r - yr * HP;
    const float* s = ssn + n * (H * W);
    float acc = 0.f;
    #pragma unroll
    for (int dy = 0; dy < 3; dy++)
        #pragma unroll
        for (int dx = 0; dx < 3; dx++)
            acc += s[(yr + dy) * W + (xr + dx)];
    invn[t] = 1.0f / (sqrtf(acc) + 1e-5f);
}

// ---------------- Kernel 3: fused GEMM (8836 x 8836 x 576) + running argmax ----------------
// grid: (70 m-tiles, 4 ref-segments, 2 items), block 256.
// Each thread: 8x8 register tile. K staged in LDS in chunks of 16 (one patch pixel, 16 ch).
__global__ __launch_bounds__(256, 3) void corr_kernel(
    const float* __restrict__ fiN, const float* __restrict__ frN,
    const float* __restrict__ invn,
    float* __restrict__ bestv, int* __restrict__ besti)
{
    __shared__ union SM {
        struct { float A[KC][MT]; float B[KC][NT]; } g;       // 8KB + 8KB
        struct { float rv[MT][16]; int ri[MT][16]; } red;     // 8KB + 8KB
    } sm;

    const int t = threadIdx.x;
    const int itile = blockIdx.x;
    const int seg = blockIdx.y;
    const int n = blockIdx.z;

    const float* fa = fiN + (size_t)n * H * W * C;
    const float* fb = frN + (size_t)n * H * W * C;
    const float* inv = invn + (size_t)n * NP;

    // Loader mapping: thread loads float4 at rows (t>>2) and (t>>2)+64, channel offset (t&3)*4
    const int lrow = t >> 2;
    const int lc = (t & 3) * 4;

    // A rows fixed for whole kernel
    int ia0 = itile * MT + lrow;      if (ia0 > NP - 1) ia0 = NP - 1;
    int ia1 = itile * MT + lrow + 64; if (ia1 > NP - 1) ia1 = NP - 1;
    const int ay0 = ia0 / HP, ax0 = ia0 - ay0 * HP;
    const int ay1 = ia1 / HP, ax1 = ia1 - ay1 * HP;
    const int aoff0 = (ay0 * W + ax0) * C;
    const int aoff1 = (ay1 * W + ax1) * C;

    // Compute-tile mapping: 8 rows x 8 cols per thread
    const int tm = (t & 15) * 8;
    const int tn = (t >> 4) * 8;

    const int segStart = seg * SEGLEN;
    const int segEnd = segStart + SEGLEN;

    float bv[8];
    int bi[8];
    #pragma unroll
    for (int i = 0; i < 8; i++) { bv[i] = -INFINITY; bi[i] = 0; }

    for (int rt = segStart; rt < segEnd; rt += NT) {
        int ib0 = rt + lrow;      if (ib0 > NP - 1) ib0 = NP - 1;
        int ib1 = rt + lrow + 64; if (ib1 > NP - 1) ib1 = NP - 1;
        const int by0 = ib0 / HP, bx0 = ib0 - by0 * HP;
        const int by1 = ib1 / HP, bx1 = ib1 - by1 * HP;
        const int boff0 = (by0 * W + bx0) * C;
        const int boff1 = (by1 * W + bx1) * C;

        float acc[8][8];
        #pragma unroll
        for (int i = 0; i < 8; i++)
            #pragma unroll
            for (int j = 0; j < 8; j++) acc[i][j] = 0.f;

        #pragma unroll 1
        for (int ch = 0; ch < 36; ch++) {
            const int pp = ch >> 2;           // patch pixel 0..8
            const int c0 = (ch & 3) << 4;     // channel base 0,16,32,48
            const int dy = pp / 3, dx = pp - dy * 3;
            const int poff = (dy * W + dx) * C + c0 + lc;

            float4 a0 = *(const float4*)(fa + aoff0 + poff);
            float4 a1 = *(const float4*)(fa + aoff1 + poff);
            float4 b0 = *(const float4*)(fb + boff0 + poff);
            float4 b1 = *(const float4*)(fb + boff1 + poff);

            __syncthreads();  // previous chunk's LDS reads complete
            sm.g.A[lc + 0][lrow] = a0.x; sm.g.A[lc + 1][lrow] = a0.y;
            sm.g.A[lc + 2][lrow] = a0.z; sm.g.A[lc + 3][lrow] = a0.w;
            sm.g.A[lc + 0][lrow + 64] = a1.x; sm.g.A[lc + 1][lrow + 64] = a1.y;
            sm.g.A[lc + 2][lrow + 64] = a1.z; sm.g.A[lc + 3][lrow + 64] = a1.w;
            sm.g.B[lc + 0][lrow] = b0.x; sm.g.B[lc + 1][lrow] = b0.y;
            sm.g.B[lc + 2][lrow] = b0.z; sm.g.B[lc + 3][lrow] = b0.w;
            sm.g.B[lc + 0][lrow + 64] = b1.x; sm.g.B[lc + 1][lrow + 64] = b1.y;
            sm.g.B[lc + 2][lrow + 64] = b1.z; sm.g.B[lc + 3][lrow + 64] = b1.w;
            __syncthreads();

            #pragma unroll
            for (int k = 0; k < KC; k++) {
                float4 af0 = *(const float4*)&sm.g.A[k][tm];
                float4 af1 = *(const float4*)&sm.g.A[k][tm + 4];
                float4 bf0 = *(const float4*)&sm.g.B[k][tn];
                float4 bf1 = *(const float4*)&sm.g.B[k][tn + 4];
                float av[8] = {af0.x, af0.y, af0.z, af0.w, af1.x, af1.y, af1.z, af1.w};
                float bw[8] = {bf0.x, bf0.y, bf0.z, bf0.w, bf1.x, bf1.y, bf1.z, bf1.w};
                #pragma unroll
                for (int i = 0; i < 8; i++)
                    #pragma unroll
                    for (int j = 0; j < 8; j++)
                        acc[i][j] = fmaf(av[i], bw[j], acc[i][j]);
            }
        }

        // epilogue: scale by ref inverse norm, update running argmax (r increasing => '>' keeps first)
        #pragma unroll
        for (int j = 0; j < 8; j++) {
            int r = rt + tn + j;
            bool valid = (r < segEnd);
            int rc = valid ? r : 0;
            float iv = inv[rc];
            #pragma unroll
            for (int i = 0; i < 8; i++) {
                float v = acc[i][j] * iv;
                if (valid && v > bv[i]) { bv[i] = v; bi[i] = r; }
            }
        }
    }

    // Cross-thread (tn-group) lexicographic reduction via LDS
    __syncthreads();
    #pragma unroll
    for (int i = 0; i < 8; i++) {
        sm.red.rv[tm + i][t >> 4] = bv[i];
        sm.red.ri[tm + i][t >> 4] = bi[i];
    }
    __syncthreads();
    if (t < MT) {
        float v = sm.red.rv[t][0];
        int idx = sm.red.ri[t][0];
        #pragma unroll
        for (int j = 1; j < 16; j++) {
            float v2 = sm.red.rv[t][j];
            int i2 = sm.red.ri[t][j];
            if (v2 > v || (v2 == v && i2 < idx)) { v = v2; idx = i2; }
        }
        int gi = itile * MT + t;
        if (gi < NP) {
            size_t o = ((size_t)n * NSEG + seg) * NP + gi;
            bestv[o] = v;
            besti[o] = idx;
        }
    }
}

// ---------------- Kernel 4: reduce segments -> flow ----------------
__global__ __launch_bounds__(256) void reduce_flow_kernel(
    const float* __restrict__ bestv, const int* __restrict__ besti,
    float* __restrict__ flowh, float* __restrict__ floww)
{
    int t = blockIdx.x * 256 + threadIdx.x;
    if (t >= NITEM * NP) return;
    int n = t / NP;
    int i = t - n * NP;
    const float* bvp = bestv + (size_t)n * NSEG * NP;
    const int* bip = besti + (size_t)n * NSEG * NP;
    float v = bvp[i];
    int idx = bip[i];
    #pragma unroll
    for (int s = 1; s < NSEG; s++) {
        float v2 = bvp[s * NP + i];
        int i2 = bip[s * NP + i];
        if (v2 > v || (v2 == v && i2 < idx)) { v = v2; idx = i2; }
    }
    int yi = i / HP, xi = i - yi * HP;
    int yr = idx / HP, xr = idx - yr * HP;
    flowh[t] = (float)(yr - yi);
    floww[t] = (float)(xr - xi);
}

// ---------------- Kernel 5: expand to 9 shifted copies, channel-interleaved output ----------------
__global__ __launch_bounds__(256) void expand_kernel(
    const float* __restrict__ flowh, const float* __restrict__ floww,
    float* __restrict__ out)
{
    int t = blockIdx.x * 256 + threadIdx.x;
    const int total = NITEM * 18 * H * W;
    if (t >= total) return;
    int x = t % W;
    int y = (t / W) % H;
    int chn = (t / (H * W)) % 18;
    int n = t / (18 * H * W);
    int k = chn >> 1;
    int b = chn & 1;          // 0 -> flow_h, 1 -> flow_w
    int is = k / 3, js = k - is * 3;
    int ys = y - is, xs = x - js;
    float val = 0.f;
    if (ys >= 0 && ys < HP && xs >= 0 && xs < HP) {
        int src = n * NP + ys * HP + xs;
        val = b ? floww[src] : flowh[src];
    }
    out[t] = val;
}

// ---------------- Launch ----------------
extern "C" void kernel_launch(void* const* d_in, const int* in_sizes, int n_in,
                              void* d_out, int out_size, void* d_ws, size_t ws_size,
                              hipStream_t stream) {
    (void)in_sizes; (void)n_in; (void)out_size; (void)ws_size;
    const float* f1 = (const float*)d_in[0];
    const float* f2 = (const float*)d_in[1];
    float* ws = (float*)d_ws;

    float* fiN   = ws;                                  // 2*9216*64
    float* frN   = fiN + NITEM * H * W * C;             // 2*9216*64
    float* ssn   = frN + NITEM * H * W * C;             // 2*9216
    float* invn  = ssn + NITEM * H * W;                 // 2*8836
    float* bestv = invn + NITEM * NP;                   // 2*4*8836
    int*   besti = (int*)(bestv + NITEM * NSEG * NP);   // 2*4*8836
    float* flowh = (float*)(besti + NITEM * NSEG * NP); // 2*8836
    float* floww = flowh + NITEM * NP;                  // 2*8836

    {
        int nthreads = 2 * NITEM * H * W;
        normalize_kernel<<<(nthreads + 255) / 256, 256, 0, stream>>>(f1, f2, fiN, frN, ssn);
    }
    {
        int nthreads = NITEM * NP;
        refnorm_kernel<<<(nthreads + 255) / 256, 256, 0, stream>>>(ssn, invn);
    }
    {
        dim3 grid(NMTILE, NSEG, NITEM);
        corr_kernel<<<grid, 256, 0, stream>>>(fiN, frN, invn, bestv, besti);
    }
    {
        int nthreads = NITEM * NP;
        reduce_flow_kernel<<<(nthreads + 255) / 256, 256, 0, stream>>>(bestv, besti, flowh, floww);
    }
    {
        int nthreads = NITEM * 18 * H * W;
        expand_kernel<<<(nthreads + 255) / 256, 256, 0, stream>>>(flowh, floww, (float*)d_out);
    }
}